// Round 1
// baseline (127.804 us; speedup 1.0000x reference)
//
#include <hip/hip_runtime.h>

#define DIM 128
#define NVOX (DIM*DIM*DIM)

#define TD 4
#define TH 8
#define TW 16
#define HD (TD+2)   // 6
#define HH (TH+2)   // 10
#define HW (TW+2)   // 18
#define HALO (HD*HH*HW)  // 1080

// Transpose KL_weight (27, 3,3,3,3) -> Wt[t][c], t = ((m*3+di)*3+dj)*3+dk, c = out channel.
__global__ void transpose_w_kernel(const float* __restrict__ W, float* __restrict__ Wt) {
    int i = blockIdx.x * 256 + threadIdx.x;
    if (i < 27 * 81) {
        int c = i / 81;
        int t = i % 81;
        Wt[t * 27 + c] = W[i];
    }
}

__global__ __launch_bounds__(256) void invo_fused_kernel(
    const float* __restrict__ img,   // (3, D, H, W)
    const float* __restrict__ x,     // (4, 1, D, H, W)
    const float* __restrict__ Wt,    // (81, 27) transposed weights
    const float* __restrict__ bias,  // (27,)
    float* __restrict__ out)         // (4, 1, D, H, W)
{
    __shared__ float sImg[3][HD][HH][HW];
    __shared__ float sX[HD][HH][HW][4];   // batch innermost -> b128 reads

    const int w0 = blockIdx.x * TW;
    const int h0 = blockIdx.y * TH;
    const int d0 = blockIdx.z * TD;

    // ---- stage halos into LDS ----
    for (int idx = threadIdx.x; idx < HALO; idx += 256) {
        int lw = idx % HW;
        int lh = (idx / HW) % HH;
        int ld = idx / (HW * HH);
        int gd = d0 - 1 + ld, gh = h0 - 1 + lh, gw = w0 - 1 + lw;
        bool ok = (unsigned)gd < DIM && (unsigned)gh < DIM && (unsigned)gw < DIM;
        long gi = ((long)gd * DIM + gh) * DIM + gw;

        float i0 = 0.f, i1 = 0.f, i2 = 0.f;
        float4 xv = make_float4(0.f, 0.f, 0.f, 0.f);
        if (ok) {
            i0 = img[0 * NVOX + gi];
            i1 = img[1 * NVOX + gi];
            i2 = img[2 * NVOX + gi];
            xv.x = x[0 * NVOX + gi];
            xv.y = x[1 * NVOX + gi];
            xv.z = x[2 * NVOX + gi];
            xv.w = x[3 * NVOX + gi];
        }
        float* simg = &sImg[0][0][0][0];
        simg[0 * HALO + idx] = i0;
        simg[1 * HALO + idx] = i1;
        simg[2 * HALO + idx] = i2;
        *reinterpret_cast<float4*>(&sX[0][0][0][0] + (long)idx * 4) = xv;
    }
    __syncthreads();

    // ---- compute: each thread handles 2 voxels along d ----
    const int lw  = threadIdx.x & (TW - 1);
    const int lh  = (threadIdx.x / TW) & (TH - 1);
    const int ld2 = threadIdx.x / (TW * TH);   // 0..1

    for (int sub = 0; sub < 2; ++sub) {
        const int ld = ld2 * 2 + sub;

        float K[27];
        #pragma unroll
        for (int c = 0; c < 27; ++c) K[c] = bias[c];

        // K-conv: 81 taps, 27 output channels each
        for (int md = 0; md < 9; ++md) {      // md = m*3 + di
            const int m  = md / 3;
            const int di = md % 3;
            #pragma unroll
            for (int dj = 0; dj < 3; ++dj) {
                #pragma unroll
                for (int dk = 0; dk < 3; ++dk) {
                    const float v = sImg[m][ld + di][lh + dj][lw + dk];
                    const int t = md * 9 + dj * 3 + dk;
                    #pragma unroll
                    for (int c = 0; c < 27; ++c)
                        K[c] = fmaf(v, Wt[t * 27 + c], K[c]);
                }
            }
        }

        // dynamic apply: y[b] = sum_c x[b, pos+off(c)] * K[c]
        float y0 = 0.f, y1 = 0.f, y2 = 0.f, y3 = 0.f;
        #pragma unroll
        for (int di = 0; di < 3; ++di) {
            #pragma unroll
            for (int dj = 0; dj < 3; ++dj) {
                #pragma unroll
                for (int dk = 0; dk < 3; ++dk) {
                    const float4 xv = *reinterpret_cast<const float4*>(&sX[ld + di][lh + dj][lw + dk][0]);
                    const float k = K[di * 9 + dj * 3 + dk];
                    y0 = fmaf(xv.x, k, y0);
                    y1 = fmaf(xv.y, k, y1);
                    y2 = fmaf(xv.z, k, y2);
                    y3 = fmaf(xv.w, k, y3);
                }
            }
        }

        const long o = ((long)(d0 + ld) * DIM + (h0 + lh)) * DIM + (w0 + lw);
        out[0 * NVOX + o] = y0;
        out[1 * NVOX + o] = y1;
        out[2 * NVOX + o] = y2;
        out[3 * NVOX + o] = y3;
    }
}

extern "C" void kernel_launch(void* const* d_in, const int* in_sizes, int n_in,
                              void* d_out, int out_size, void* d_ws, size_t ws_size,
                              hipStream_t stream) {
    const float* img  = (const float*)d_in[0];
    const float* x    = (const float*)d_in[1];
    const float* W    = (const float*)d_in[2];
    const float* bias = (const float*)d_in[3];
    float* out = (float*)d_out;
    float* Wt  = (float*)d_ws;   // 2187 floats = 8.75 KB

    transpose_w_kernel<<<(27 * 81 + 255) / 256, 256, 0, stream>>>(W, Wt);

    dim3 grid(DIM / TW, DIM / TH, DIM / TD);   // (8, 16, 32)
    invo_fused_kernel<<<grid, 256, 0, stream>>>(img, x, Wt, bias, out);
}

// Round 2
// 61.037 us; speedup vs baseline: 2.0939x; 2.0939x over previous
//
#include <hip/hip_runtime.h>

#define DIM 128
#define NVOX (DIM*DIM*DIM)
#define TD 4
#define TH 8
#define TW 16
#define HD 6
#define HH 10
#define HW 18
#define HALO (HD*HH*HW)   // 1080 cells

typedef __attribute__((ext_vector_type(8))) __bf16 bf16x8;
typedef __attribute__((ext_vector_type(8))) short  short8;
typedef __attribute__((ext_vector_type(4))) float  f32x4;

static __device__ __host__ __forceinline__ unsigned short f2bf(float f) {
    union { float f; unsigned u; } v; v.f = f;
    unsigned r = v.u + 0x7FFFu + ((v.u >> 16) & 1u);   // RNE
    return (unsigned short)(r >> 16);
}

// Prep: Wa[mm][T][lane][i] = bf16 of W[ch=T*16+(lane&15)][k=mm*32 + (lane>>4)*8+i]
// (zero for ch>=27 or tap>=27); bias32 = bias zero-padded to 32.
__global__ void prep_kernel(const float* __restrict__ W, const float* __restrict__ bias,
                            unsigned short* __restrict__ Wa, float* __restrict__ bias32) {
    int idx = blockIdx.x * 256 + threadIdx.x;
    if (idx < 3072) {
        int i  = idx & 7;
        int l  = (idx >> 3) & 63;
        int T  = (idx >> 9) & 1;
        int mm = idx >> 10;
        int ch  = T * 16 + (l & 15);
        int tap = (l >> 4) * 8 + i;   // 0..31
        float w = 0.f;
        if (ch < 27 && tap < 27) w = W[ch * 81 + mm * 27 + tap];  // (27,3,3,3,3) flat
        Wa[idx] = f2bf(w);
    } else if (idx < 3072 + 32) {
        int c = idx - 3072;
        bias32[c] = (c < 27) ? bias[c] : 0.f;
    }
}

__global__ __launch_bounds__(256) void invo_mfma_kernel(
    const float* __restrict__ img,   // (3, D,H,W) f32
    const float* __restrict__ x,     // (4, 1, D,H,W) f32
    const unsigned short* __restrict__ Wa,
    const float* __restrict__ bias32,
    float* __restrict__ out)         // (4, 1, D,H,W) f32
{
    __shared__ unsigned short sImg[3 * HALO];   // bf16 halo, [m][ld][lh][lw]
    __shared__ unsigned short sX[HALO * 4];     // bf16 [cell][batch0..3] (8B/cell)

    const int w0 = blockIdx.x * TW, h0 = blockIdx.y * TH, d0 = blockIdx.z * TD;
    const int tid = threadIdx.x;

    // ---- stage halos (bf16) ----
    for (int idx = tid; idx < HALO; idx += 256) {
        int lw = idx % HW, lh = (idx / HW) % HH, ld = idx / (HW * HH);
        int gd = d0 - 1 + ld, gh = h0 - 1 + lh, gw = w0 - 1 + lw;
        bool ok = (unsigned)gd < DIM && (unsigned)gh < DIM && (unsigned)gw < DIM;
        long gi = ((long)gd * DIM + gh) * DIM + gw;
        float i0 = 0, i1 = 0, i2 = 0, x0 = 0, x1 = 0, x2 = 0, x3 = 0;
        if (ok) {
            i0 = img[gi]; i1 = img[NVOX + gi]; i2 = img[2 * NVOX + gi];
            x0 = x[gi]; x1 = x[NVOX + gi]; x2 = x[2 * NVOX + gi]; x3 = x[3 * NVOX + gi];
        }
        sImg[idx] = f2bf(i0); sImg[HALO + idx] = f2bf(i1); sImg[2 * HALO + idx] = f2bf(i2);
        unsigned p01 = (unsigned)f2bf(x0) | ((unsigned)f2bf(x1) << 16);
        unsigned p23 = (unsigned)f2bf(x2) | ((unsigned)f2bf(x3) << 16);
        *reinterpret_cast<uint2*>(&sX[idx * 4]) = make_uint2(p01, p23);
    }
    __syncthreads();

    const int lane = tid & 63;
    const int wv   = tid >> 6;       // wave 0..3
    const int v    = lane & 15;      // voxel (w) within the 16-run
    const int g    = lane >> 4;      // lane group 0..3

    // gather offsets (elements) for taps t = 8g+j; pad taps -> 0 (weight is 0)
    int d3[8];
    #pragma unroll
    for (int j = 0; j < 8; ++j) {
        int t = 8 * g + j;
        if (t < 27) {
            int di = t / 9, rj = t - 9 * di, dj = rj / 3, dk = rj - 3 * dj;
            d3[j] = di * (HH * HW) + dj * HW + dk;
        } else d3[j] = 0;
    }
    // apply-step x cell offsets for this lane's channels
    int xo0[4], xo1[4];
    #pragma unroll
    for (int r = 0; r < 4; ++r) {
        int c = 4 * g + r;
        { int i3 = c / 9, rr = c - 9 * i3, j3 = rr / 3, k3 = rr - 3 * j3;
          xo0[r] = i3 * (HH * HW) + j3 * HW + k3; }
        int c1 = 16 + 4 * g + r;
        if (c1 < 27) {
            int i3 = c1 / 9, rr = c1 - 9 * i3, j3 = rr / 3, k3 = rr - 3 * j3;
            xo1[r] = i3 * (HH * HW) + j3 * HW + k3;
        } else xo1[r] = 0;
    }

    // hoist A fragments + bias
    bf16x8 afrag[3][2];
    #pragma unroll
    for (int m = 0; m < 3; ++m)
        #pragma unroll
        for (int T = 0; T < 2; ++T)
            afrag[m][T] = *reinterpret_cast<const bf16x8*>(&Wa[((m * 2 + T) * 64 + lane) * 8]);
    f32x4 b0 = *reinterpret_cast<const f32x4*>(&bias32[4 * g]);
    f32x4 b1 = *reinterpret_cast<const f32x4*>(&bias32[16 + 4 * g]);

    const uint2* sXc = reinterpret_cast<const uint2*>(sX);

    for (int it = 0; it < 8; ++it) {
        const int run = wv * 8 + it;          // 0..31
        const int ld = run >> 3, lh = run & 7;
        const int base = ld * (HH * HW) + lh * HW + v;

        f32x4 acc0 = {0.f, 0.f, 0.f, 0.f}, acc1 = {0.f, 0.f, 0.f, 0.f};
        #pragma unroll
        for (int m = 0; m < 3; ++m) {
            short8 bs;
            #pragma unroll
            for (int j = 0; j < 8; ++j)
                bs[j] = (short)sImg[m * HALO + base + d3[j]];
            bf16x8 bfrag = __builtin_bit_cast(bf16x8, bs);
            acc0 = __builtin_amdgcn_mfma_f32_16x16x32_bf16(afrag[m][0], bfrag, acc0, 0, 0, 0);
            acc1 = __builtin_amdgcn_mfma_f32_16x16x32_bf16(afrag[m][1], bfrag, acc1, 0, 0, 0);
        }

        // apply: y[b] = sum_ch K[ch] * x[b, p+off(ch)]  (this lane's 8 channels)
        const uint2* xb = sXc + base;
        float y0 = 0, y1 = 0, y2 = 0, y3 = 0;
        #pragma unroll
        for (int r = 0; r < 4; ++r) {
            float K0 = acc0[r] + b0[r];
            float K1 = acc1[r] + b1[r];
            uint2 u0 = xb[xo0[r]];
            uint2 u1 = xb[xo1[r]];
            y0 = fmaf(K0, __uint_as_float(u0.x << 16), y0);
            y1 = fmaf(K0, __uint_as_float(u0.x & 0xFFFF0000u), y1);
            y2 = fmaf(K0, __uint_as_float(u0.y << 16), y2);
            y3 = fmaf(K0, __uint_as_float(u0.y & 0xFFFF0000u), y3);
            y0 = fmaf(K1, __uint_as_float(u1.x << 16), y0);
            y1 = fmaf(K1, __uint_as_float(u1.x & 0xFFFF0000u), y1);
            y2 = fmaf(K1, __uint_as_float(u1.y << 16), y2);
            y3 = fmaf(K1, __uint_as_float(u1.y & 0xFFFF0000u), y3);
        }

        // reduce across the 4 lane-groups holding the same voxel
        y0 += __shfl_xor(y0, 16); y0 += __shfl_xor(y0, 32);
        y1 += __shfl_xor(y1, 16); y1 += __shfl_xor(y1, 32);
        y2 += __shfl_xor(y2, 16); y2 += __shfl_xor(y2, 32);
        y3 += __shfl_xor(y3, 16); y3 += __shfl_xor(y3, 32);

        // lane-group g stores batch g
        const long p = ((long)(d0 + ld) * DIM + (h0 + lh)) * DIM + (w0 + v);
        float yv = (g == 0) ? y0 : (g == 1) ? y1 : (g == 2) ? y2 : y3;
        out[(long)g * NVOX + p] = yv;
    }
}

extern "C" void kernel_launch(void* const* d_in, const int* in_sizes, int n_in,
                              void* d_out, int out_size, void* d_ws, size_t ws_size,
                              hipStream_t stream) {
    const float* img  = (const float*)d_in[0];
    const float* x    = (const float*)d_in[1];
    const float* W    = (const float*)d_in[2];
    const float* bias = (const float*)d_in[3];
    float* out = (float*)d_out;

    unsigned short* Wa = (unsigned short*)d_ws;                 // 3072 u16 = 6144 B
    float* bias32 = (float*)((char*)d_ws + 6144);               // 32 f32

    prep_kernel<<<13, 256, 0, stream>>>(W, bias, Wa, bias32);

    dim3 grid(DIM / TW, DIM / TH, DIM / TD);   // (8, 16, 32)
    invo_mfma_kernel<<<grid, 256, 0, stream>>>(img, x, Wa, bias32, out);
}